// Round 1
// baseline (17348.152 us; speedup 1.0000x reference)
//
#include <hip/hip_runtime.h>

// SimpleLSTM: V=95, H=2048, B=256, SQ=162, 15 think steps, 29 answer steps.
// Strategy: split-bf16 (hi+lo) MFMA GEMM for h @ W_hh.T each step (3-term
// error-compensated product, fp32 accumulate), fp32 everything else.

#define Hdim 2048
#define G4H  8192
#define Bsz  256
#define Vsz  95
#define SQL  162
#define TSTEPS 15
#define ASTEPS 29

typedef unsigned short u16;
typedef __attribute__((ext_vector_type(8))) short bf16x8;
typedef __attribute__((ext_vector_type(4))) float f32x4;

__device__ __forceinline__ u16 f2bf(float x) {
  unsigned u = __float_as_uint(x);
  unsigned r = (u + 0x7fffu + ((u >> 16) & 1u)) >> 16;
  return (u16)r;
}
__device__ __forceinline__ float bf2f(u16 v) {
  return __uint_as_float(((unsigned)v) << 16);
}
__device__ __forceinline__ void splitbf(float x, u16& hi, u16& lo) {
  hi = f2bf(x);
  lo = f2bf(x - bf2f(hi));
}
__device__ __forceinline__ float sigm(float x) { return 1.0f / (1.0f + expf(-x)); }

__device__ __forceinline__ void gll16(const u16* g, u16* l) {
  __builtin_amdgcn_global_load_lds(
      (const __attribute__((address_space(1))) void*)g,
      (__attribute__((address_space(3))) void*)l, 16, 0, 0);
}

// ---------------- init kernels ----------------
__global__ void k_split(const float* __restrict__ w, u16* __restrict__ whi,
                        u16* __restrict__ wlo, int n) {
  for (int i = blockIdx.x * blockDim.x + threadIdx.x; i < n;
       i += gridDim.x * blockDim.x) {
    u16 a, b;
    splitbf(w[i], a, b);
    whi[i] = a;
    wlo[i] = b;
  }
}

__global__ void k_prep(const float* __restrict__ W_ih, const float* __restrict__ b_ih,
                       const float* __restrict__ b_hh, float* __restrict__ wihT,
                       float* __restrict__ bias, float* __restrict__ h,
                       float* __restrict__ c, u16* __restrict__ h_hi,
                       u16* __restrict__ h_lo) {
  int i = blockIdx.x * 256 + threadIdx.x;
  if (i < Vsz * G4H) {
    int v = i / G4H, j = i % G4H;
    wihT[i] = W_ih[j * Vsz + v];
  }
  if (i < G4H) bias[i] = b_ih[i] + b_hh[i];
  if (i < Bsz * Hdim) {
    h[i] = 0.f;
    c[i] = 0.f;
    h_hi[i] = 0;
    h_lo[i] = 0;
  }
}

// ---------------- main GEMM: g = h @ W_hh.T + bias ----------------
// A = h (256 x 2048, bf16 hi/lo), B = W_hh (8192 x 2048, bf16 hi/lo), both K-major.
// Tile: BM=64, BN=64, BK=32. 4 waves, each 32x32 output (2x2 frags of 16x16x32).
// grid = (4, 128). 3-term split product: hi*hi + hi*lo + lo*hi.
__global__ __launch_bounds__(256) void k_gemm(
    const u16* __restrict__ a_hi, const u16* __restrict__ a_lo,
    const u16* __restrict__ b_hi, const u16* __restrict__ b_lo,
    const float* __restrict__ bias, float* __restrict__ g) {
  __shared__ __align__(16) u16 Ah[64 * 32];
  __shared__ __align__(16) u16 Al[64 * 32];
  __shared__ __align__(16) u16 Bh[64 * 32];
  __shared__ __align__(16) u16 Bl[64 * 32];

  const int tid = threadIdx.x;
  const int wave = tid >> 6, lane = tid & 63;
  const int row0 = blockIdx.x * 64;  // M tile (batch rows)
  const int col0 = blockIdx.y * 64;  // N tile (gate columns)
  const int wr = wave >> 1, wc = wave & 1;
  const int lr = lane & 15, lc = lane >> 4;

  // Each wave stages exactly one LDS array (4 x 1KB global_load_lds).
  // Source k-chunk XOR-swizzled so swizzled reads see linear data (G21).
  const u16* sbase;
  u16* lbase;
  int rbase;
  if (wave == 0)      { sbase = a_hi; rbase = row0; lbase = Ah; }
  else if (wave == 1) { sbase = a_lo; rbase = row0; lbase = Al; }
  else if (wave == 2) { sbase = b_hi; rbase = col0; lbase = Bh; }
  else                { sbase = b_lo; rbase = col0; lbase = Bl; }
  const u16* src = sbase + (long)(rbase + (lane >> 2)) * Hdim +
                   (((lane & 3) ^ ((lane >> 2) & 3)) * 8);

  // Fragment LDS pointers (constant across K loop); swizzled k-slot.
  const bf16x8 *pAh[2], *pAl[2], *pBh[2], *pBl[2];
#pragma unroll
  for (int f = 0; f < 2; ++f) {
    int ar = wr * 32 + f * 16 + lr;
    int br = wc * 32 + f * 16 + lr;
    int sl = (lc ^ (lr & 3)) * 8;
    pAh[f] = (const bf16x8*)&Ah[ar * 32 + sl];
    pAl[f] = (const bf16x8*)&Al[ar * 32 + sl];
    pBh[f] = (const bf16x8*)&Bh[br * 32 + sl];
    pBl[f] = (const bf16x8*)&Bl[br * 32 + sl];
  }

  f32x4 acc[2][2] = {};

  for (int kb = 0; kb < Hdim / 32; ++kb) {
    const u16* s = src + kb * 32;
#pragma unroll
    for (int i = 0; i < 4; ++i) gll16(s + i * 16 * Hdim, lbase + i * 512);
    __syncthreads();  // drains vmcnt before barrier -> LDS ready

    bf16x8 ah0 = *pAh[0], ah1 = *pAh[1];
    bf16x8 al0 = *pAl[0], al1 = *pAl[1];
    bf16x8 bh0 = *pBh[0], bh1 = *pBh[1];
    bf16x8 bl0 = *pBl[0], bl1 = *pBl[1];

    acc[0][0] = __builtin_amdgcn_mfma_f32_16x16x32_bf16(ah0, bh0, acc[0][0], 0, 0, 0);
    acc[0][0] = __builtin_amdgcn_mfma_f32_16x16x32_bf16(ah0, bl0, acc[0][0], 0, 0, 0);
    acc[0][0] = __builtin_amdgcn_mfma_f32_16x16x32_bf16(al0, bh0, acc[0][0], 0, 0, 0);

    acc[0][1] = __builtin_amdgcn_mfma_f32_16x16x32_bf16(ah0, bh1, acc[0][1], 0, 0, 0);
    acc[0][1] = __builtin_amdgcn_mfma_f32_16x16x32_bf16(ah0, bl1, acc[0][1], 0, 0, 0);
    acc[0][1] = __builtin_amdgcn_mfma_f32_16x16x32_bf16(al0, bh1, acc[0][1], 0, 0, 0);

    acc[1][0] = __builtin_amdgcn_mfma_f32_16x16x32_bf16(ah1, bh0, acc[1][0], 0, 0, 0);
    acc[1][0] = __builtin_amdgcn_mfma_f32_16x16x32_bf16(ah1, bl0, acc[1][0], 0, 0, 0);
    acc[1][0] = __builtin_amdgcn_mfma_f32_16x16x32_bf16(al1, bh0, acc[1][0], 0, 0, 0);

    acc[1][1] = __builtin_amdgcn_mfma_f32_16x16x32_bf16(ah1, bh1, acc[1][1], 0, 0, 0);
    acc[1][1] = __builtin_amdgcn_mfma_f32_16x16x32_bf16(ah1, bl1, acc[1][1], 0, 0, 0);
    acc[1][1] = __builtin_amdgcn_mfma_f32_16x16x32_bf16(al1, bh1, acc[1][1], 0, 0, 0);
    __syncthreads();  // protect LDS before next stage
  }

  // Epilogue: C/D layout col = lane&15, row = (lane>>4)*4 + i (m89/m91 verified)
#pragma unroll
  for (int mf = 0; mf < 2; ++mf) {
#pragma unroll
    for (int nf = 0; nf < 2; ++nf) {
      int j = col0 + wc * 32 + nf * 16 + lr;
      float bj = bias[j];
#pragma unroll
      for (int i = 0; i < 4; ++i) {
        int b = row0 + wr * 32 + mf * 16 + lc * 4 + i;
        g[(long)b * G4H + j] = acc[mf][nf][i] + bj;
      }
    }
  }
}

// ---------------- gates ----------------
// mode 0: none; mode 1: += W_ihT[tok] (one-hot input); mode 2: += ic (logits input)
__global__ __launch_bounds__(256) void k_gates(
    const float* __restrict__ g, const float* __restrict__ extra,
    const int* __restrict__ x, int t, int xstride, int mode,
    float* __restrict__ c, float* __restrict__ h, u16* __restrict__ h_hi,
    u16* __restrict__ h_lo) {
  int e = blockIdx.x * 256 + threadIdx.x;  // e = b*2048 + hh
  int b = e >> 11, hh = e & 2047;
  const float* gr = g + (long)b * G4H;
  float xi = gr[hh], xf = gr[2048 + hh], xg = gr[4096 + hh], xo = gr[6144 + hh];
  if (mode == 1) {
    int tok = x[(b * SQL + t) * xstride];
    const float* wr = extra + (long)tok * G4H;
    xi += wr[hh]; xf += wr[2048 + hh]; xg += wr[4096 + hh]; xo += wr[6144 + hh];
  } else if (mode == 2) {
    const float* icr = extra + (long)b * G4H;
    xi += icr[hh]; xf += icr[2048 + hh]; xg += icr[4096 + hh]; xo += icr[6144 + hh];
  }
  float cn = sigm(xf) * c[e] + sigm(xi) * tanhf(xg);
  float hn = sigm(xo) * tanhf(cn);
  c[e] = cn;
  h[e] = hn;
  u16 a, bb;
  splitbf(hn, a, bb);
  h_hi[e] = a;
  h_lo[e] = bb;
}

// ---------------- logits = src @ W_proj.T (fp32, exact-ish) ----------------
__global__ __launch_bounds__(256) void k_logits(const float* __restrict__ src,
                                                const float* __restrict__ Wp,
                                                float* __restrict__ lg,
                                                float* __restrict__ outp) {
  __shared__ float hl[Hdim];
  int b = blockIdx.x, tid = threadIdx.x;
  for (int k = tid; k < Hdim; k += 256) hl[k] = src[(long)b * Hdim + k];
  __syncthreads();
  int wv = tid >> 6, ln = tid & 63;
  for (int v = wv; v < Vsz; v += 4) {
    const float* wrow = Wp + (long)v * Hdim;
    float s = 0.f;
    for (int k = ln; k < Hdim; k += 64) s += wrow[k] * hl[k];
#pragma unroll
    for (int off = 32; off; off >>= 1) s += __shfl_down(s, off);
    if (ln == 0) {
      lg[b * Vsz + v] = s;
      outp[b * Vsz + v] = s;
    }
  }
}

// ---------------- ic = logits @ W_ih.T (K=95, fp32) ----------------
__global__ __launch_bounds__(256) void k_ic(const float* __restrict__ lg,
                                            const float* __restrict__ wihT,
                                            float* __restrict__ ic) {
  __shared__ float ll[8 * Vsz];
  int jg = blockIdx.x, bg = blockIdx.y, tid = threadIdx.x;
  int j = jg * 256 + tid;
  for (int i = tid; i < 8 * Vsz; i += 256) ll[i] = lg[bg * 8 * Vsz + i];
  __syncthreads();
  float a[8] = {0, 0, 0, 0, 0, 0, 0, 0};
  for (int v = 0; v < Vsz; ++v) {
    float w = wihT[(long)v * G4H + j];
#pragma unroll
    for (int bb = 0; bb < 8; ++bb) a[bb] += ll[bb * Vsz + v] * w;
  }
#pragma unroll
  for (int bb = 0; bb < 8; ++bb) ic[(long)(bg * 8 + bb) * G4H + j] = a[bb];
}

// ---------------- host ----------------
extern "C" void kernel_launch(void* const* d_in, const int* in_sizes, int n_in,
                              void* d_out, int out_size, void* d_ws, size_t ws_size,
                              hipStream_t stream) {
  const int* x = (const int*)d_in[0];
  const float* W_ih = (const float*)d_in[1];
  const float* W_hh = (const float*)d_in[2];
  const float* b_ih = (const float*)d_in[3];
  const float* b_hh = (const float*)d_in[4];
  const float* W_proj = (const float*)d_in[5];
  float* out = (float*)d_out;

  // hedge against int64 tokens kept as 2x int32 (little-endian, values < 95)
  int xstride = (in_sizes[0] > Bsz * SQL) ? 2 : 1;

  // workspace layout (~95.5 MB)
  u16* whh_hi = (u16*)d_ws;
  u16* whh_lo = whh_hi + (long)G4H * Hdim;
  float* wihT = (float*)(whh_lo + (long)G4H * Hdim);
  float* bias = wihT + (long)Vsz * G4H;
  float* g    = bias + G4H;
  float* ic   = g + (long)Bsz * G4H;
  float* h    = ic + (long)Bsz * G4H;
  float* c    = h + (long)Bsz * Hdim;
  float* outq = c + (long)Bsz * Hdim;
  float* lg   = outq + (long)Bsz * Hdim;
  u16* h_hi   = (u16*)(lg + Bsz * Vsz);
  u16* h_lo   = h_hi + (long)Bsz * Hdim;

  k_split<<<4096, 256, 0, stream>>>(W_hh, whh_hi, whh_lo, G4H * Hdim);
  k_prep<<<3040, 256, 0, stream>>>(W_ih, b_ih, b_hh, wihT, bias, h, c, h_hi, h_lo);

  dim3 ggrid(4, 128);

  // Phase 1: question (one-hot gather input)
  for (int t = 0; t < SQL; ++t) {
    k_gemm<<<ggrid, 256, 0, stream>>>(h_hi, h_lo, whh_hi, whh_lo, bias, g);
    k_gates<<<2048, 256, 0, stream>>>(g, wihT, x, t, xstride, 1, c, h, h_hi, h_lo);
  }
  // out_q = h after question loop
  hipMemcpyAsync(outq, h, (long)Bsz * Hdim * sizeof(float),
                 hipMemcpyDeviceToDevice, stream);

  // Phase 2: thinking (zero input)
  for (int t = 0; t < TSTEPS; ++t) {
    k_gemm<<<ggrid, 256, 0, stream>>>(h_hi, h_lo, whh_hi, whh_lo, bias, g);
    k_gates<<<2048, 256, 0, stream>>>(g, nullptr, nullptr, 0, 1, 0, c, h, h_hi, h_lo);
  }

  // Phase 3: autoregressive answer (logits fed back)
  for (int s = 0; s < ASTEPS; ++s) {
    const float* src = (s == 0) ? outq : h;
    k_logits<<<Bsz, 256, 0, stream>>>(src, W_proj, lg, out + (long)s * Bsz * Vsz);
    k_ic<<<dim3(32, 32), 256, 0, stream>>>(lg, wihT, ic);
    k_gemm<<<ggrid, 256, 0, stream>>>(h_hi, h_lo, whh_hi, whh_lo, bias, g);
    k_gates<<<2048, 256, 0, stream>>>(g, ic, nullptr, 0, 1, 2, c, h, h_hi, h_lo);
  }
}